// Round 6
// baseline (15.631 us; speedup 1.0000x reference)
//
#include <hip/hip_runtime.h>

// R6 = R5 + DCE-protected VALU decoy — a timing-floor falsification probe.
// R3/R4/R5 (structurally disjoint) all measured 9.76-9.86 us while pipe
// arithmetic puts the kernel body at ~2-3 us -> hypothesis: dur_us is a
// graph-replay launch floor (~9.8 us), kernel time invisible below it.
// This kernel adds ~1280 FMA/thread (~+4-5 us GPU) whose inputs are made
// opaque per-rep via asm volatile (guide rule #17) so they cannot be
// CSE'd/DCE'd, and whose results are sunk via asm. Output is bit-identical
// to R5. If dur_us stays ~9.8 -> floor confirmed, revert to R5 and declare.
// If dur_us rises by ~ the decoy cost -> kernel time is visible; keep digging.
//
// Math (verified r1-r5, absmax 1.95e-3):
//   c_i = cos(x_i + theta_i); z[0]=c1..c7, z[w]=c0..cw (w>=1).
//   G = z z^T / sqrt(8); attn = softmax rows (no max-pass, |s|<=2.83);
//   o = attn @ z; y = o @ W^T + b  (MFMA 16x16x32 bf16, m89 fragment maps).

#define TOK_PER_BLK 16
#define DECOY_REPS 40

typedef __attribute__((ext_vector_type(8))) short short8;
typedef __attribute__((ext_vector_type(4))) float f32x4;

__device__ inline unsigned short f2bf(float f) {
    unsigned u = __float_as_uint(f);
    u += 0x7FFF + ((u >> 16) & 1);          // RNE
    return (unsigned short)(u >> 16);
}

__device__ inline short8 pack_bf16x8(float4 a, float4 b) {
    short8 r;
    r[0] = (short)f2bf(a.x); r[1] = (short)f2bf(a.y);
    r[2] = (short)f2bf(a.z); r[3] = (short)f2bf(a.w);
    r[4] = (short)f2bf(b.x); r[5] = (short)f2bf(b.y);
    r[6] = (short)f2bf(b.z); r[7] = (short)f2bf(b.w);
    return r;
}

__global__ __launch_bounds__(256, 4)
void mhaq_fused6(const float* __restrict__ x,
                 const float* __restrict__ theta,
                 const float* __restrict__ W,
                 const float* __restrict__ bias,
                 float* __restrict__ out,
                 int n_tokens)
{
    __shared__ __align__(16) float          zs[TOK_PER_BLK * 68]; // f32, pad 4
    __shared__ __align__(16) unsigned short os[TOK_PER_BLK * 72]; // bf16, pad 8

    const int tid  = threadIdx.x;
    const int tl   = tid >> 4;          // token within block, 0..15
    const int s    = tid & 15;
    const int h    = s >> 1;            // head this thread attends
    const int half = s & 1;             // t-range / d-range half
    const int blockbase = blockIdx.x * TOK_PER_BLK;
    const int token = blockbase + tl;
    const bool zrole = (s < 8);

    // ---- x load FIRST (phase-1 critical path) ----
    float4 xa = make_float4(0.f, 0.f, 0.f, 0.f);
    float4 xb = make_float4(0.f, 0.f, 0.f, 0.f);
    if (zrole && token < n_tokens) {
        const float4* __restrict__ xp =
            reinterpret_cast<const float4*>(x) + (size_t)token * 16 + s * 2;
        xa = xp[0]; xb = xp[1];
    }

    // ---- W + bias prefetch (consumed in phase 3, after 2 barriers) ----
    const int lane = tid & 63;
    const int wave = tid >> 6;          // 0..3 -> j-quarter
    const int lr   = lane & 15;
    const int lg   = lane >> 4;         // 0..3
    const int j    = wave * 16 + lr;
    float4 wf[2][2];                    // [kt][half8]
    float  bj = bias[j];
    {
        const float4* __restrict__ Wv = reinterpret_cast<const float4*>(W);
        #pragma unroll
        for (int kt = 0; kt < 2; ++kt) {
            int fidx = (j * 64 + kt * 32 + lg * 8) >> 2;
            wf[kt][0] = Wv[fidx];
            wf[kt][1] = Wv[fidx + 1];
        }
    }

    // ---- phase 1: threads s<8 compute z for head s ----
    if (zrole) {
        float c0 = __cosf(xa.x + theta[0]);
        float c1 = __cosf(xa.y + theta[1]);
        float c2 = __cosf(xa.z + theta[2]);
        float c3 = __cosf(xa.w + theta[3]);
        float c4 = __cosf(xb.x + theta[4]);
        float c5 = __cosf(xb.y + theta[5]);
        float c6 = __cosf(xb.z + theta[6]);
        float c7 = __cosf(xb.w + theta[7]);
        float p1 = c0 * c1;
        float p2 = p1 * c2;
        float p3 = p2 * c3;
        float p4 = p3 * c4;
        float p5 = p4 * c5;
        float p6 = p5 * c6;
        float p7 = p6 * c7;
        float s6 = c6 * c7;
        float s5 = c5 * s6;
        float s4 = c4 * s5;
        float s3 = c3 * s4;
        float s2 = c2 * s3;
        float s1 = c1 * s2;             // c1*...*c7
        float4* z4 = reinterpret_cast<float4*>(zs + tl * 68 + s * 8);
        z4[0] = make_float4(s1, p1, p2, p3);
        z4[1] = make_float4(p4, p5, p6, p7);
    }
    __syncthreads();

    // ---- phase 2: head h, halves of t and d; o -> bf16 LDS ----
    {
        const float* zrow = zs + tl * 68;
        float zh[8];
        *reinterpret_cast<float4*>(&zh[0]) =
            *reinterpret_cast<const float4*>(&zrow[h * 8]);
        *reinterpret_cast<float4*>(&zh[4]) =
            *reinterpret_cast<const float4*>(&zrow[h * 8 + 4]);

        // score rows: t = half*4 .. half*4+3 (contiguous 32 floats)
        float zt[32];
        #pragma unroll
        for (int i = 0; i < 8; ++i)
            *reinterpret_cast<float4*>(&zt[i * 4]) =
                *reinterpret_cast<const float4*>(&zrow[half * 32 + i * 4]);

        const float scale = 0.35355339059327373f;  // 1/sqrt(8)
        float e[4];
        float psum = 0.f;
        #pragma unroll
        for (int tt = 0; tt < 4; ++tt) {
            float sd = 0.f;
            #pragma unroll
            for (int d = 0; d < 8; ++d)
                sd = fmaf(zh[d], zt[tt * 8 + d], sd);
            e[tt] = __expf(sd * scale);
            psum += e[tt];
        }
        float tot = psum + __shfl_xor(psum, 1, 64);
        float inv = 1.0f / tot;

        // ---- DECOY: floor-falsification probe (no effect on output) ----
        // ~32 FMA per rep; per-rep opaque seed defeats CSE; sinks defeat DCE.
        #pragma unroll 1
        for (int rep = 0; rep < DECOY_REPS; ++rep) {
            float seed = zh[0];
            asm volatile("" : "+v"(seed));      // opaque: forces recompute
            float a0 = seed, a1 = seed, a2 = seed, a3 = seed;
            #pragma unroll
            for (int d = 0; d < 8; ++d) {
                a0 = fmaf(zh[d], zt[d],      a0);
                a1 = fmaf(zh[d], zt[8 + d],  a1);
                a2 = fmaf(zh[d], zt[16 + d], a2);
                a3 = fmaf(zh[d], zt[24 + d], a3);
            }
            asm volatile("" :: "v"(a0), "v"(a1), "v"(a2), "v"(a3)); // sink
        }
        // ---- end decoy ----

        float ep[4];
        #pragma unroll
        for (int tt = 0; tt < 4; ++tt)
            ep[tt] = __shfl_xor(e[tt], 1, 64);

        // full e in t-order (static indices; per-element select, rule #20)
        float ef[8];
        #pragma unroll
        for (int tt = 0; tt < 4; ++tt) {
            ef[tt]     = half ? ep[tt] : e[tt];
            ef[4 + tt] = half ? e[tt]  : ep[tt];
        }

        // column slice: z[t][half*4 + dd], t=0..7
        float zc[32];
        #pragma unroll
        for (int t = 0; t < 8; ++t)
            *reinterpret_cast<float4*>(&zc[t * 4]) =
                *reinterpret_cast<const float4*>(&zrow[t * 8 + half * 4]);

        unsigned short oh[4];
        #pragma unroll
        for (int dd = 0; dd < 4; ++dd) {
            float acc = 0.f;
            #pragma unroll
            for (int t = 0; t < 8; ++t)
                acc = fmaf(ef[t], zc[t * 4 + dd], acc);
            oh[dd] = f2bf(acc * inv);
        }
        *reinterpret_cast<ushort4*>(&os[tl * 72 + h * 8 + half * 4]) =
            make_ushort4(oh[0], oh[1], oh[2], oh[3]);
    }
    __syncthreads();

    // ---- phase 3: y = o @ W^T + b via MFMA; W frags from registers ----
    {
        short8 afrag[2];
        #pragma unroll
        for (int kt = 0; kt < 2; ++kt)
            afrag[kt] = *reinterpret_cast<const short8*>(
                &os[lr * 72 + kt * 32 + lg * 8]);

        f32x4 acc = {bj, bj, bj, bj};
        #pragma unroll
        for (int kt = 0; kt < 2; ++kt) {
            short8 bfrag = pack_bf16x8(wf[kt][0], wf[kt][1]);
            acc = __builtin_amdgcn_mfma_f32_16x16x32_bf16(
                afrag[kt], bfrag, acc, 0, 0, 0);
        }
        #pragma unroll
        for (int r = 0; r < 4; ++r) {
            int trow = blockbase + lg * 4 + r;
            if (trow < n_tokens)
                out[(size_t)trow * 64 + j] = acc[r];
        }
    }
}

extern "C" void kernel_launch(void* const* d_in, const int* in_sizes, int n_in,
                              void* d_out, int out_size, void* d_ws, size_t ws_size,
                              hipStream_t stream)
{
    const float* x     = (const float*)d_in[0];
    const float* theta = (const float*)d_in[1];
    const float* W     = (const float*)d_in[2];
    const float* b     = (const float*)d_in[3];
    float* out         = (float*)d_out;

    const int n_tokens = in_sizes[0] / 64;                            // 16384
    const int blocks   = (n_tokens + TOK_PER_BLK - 1) / TOK_PER_BLK;  // 1024
    mhaq_fused6<<<blocks, 256, 0, stream>>>(x, theta, W, b, out, n_tokens);
}

// Round 7
// 10.978 us; speedup vs baseline: 1.4239x; 1.4239x over previous
//
#include <hip/hip_runtime.h>

// Closed form of the QLayer circuit (verified r1-r6, absmax 1.95e-3):
//   c_i = cos(x_i + theta_i); z[0]=c1..c7, z[w]=c0..cw (w>=1).
//   G = z z^T / sqrt(8); attn = softmax rows (no max-pass, |s|<=2.83);
//   o = attn @ z; y = o @ W^T + b  (MFMA 16x16x32 bf16, m89 fragment maps).
//
// R7: anti-lockstep. R6's decoy proved dur_us tracks GPU time (+5.9us for
// +4.8us issued work); R5's ~8us on-GPU vs ~3us pipe-sum gap is attributed
// to chip-wide phase lockstep (all 1024 blocks co-resident, same phase at
// same wall-time -> zero cross-block pipe overlap). Fix:
//   256 blocks x 256 thr x 4 tiles of 16 tokens, software-pipelined:
//   - tile t+1 x-loads issued before tile t compute (counted vmcnt keeps
//     them in flight across barriers)
//   - W loaded once per block, packed to bf16 once (tile-0 phase 3)
//   - longer blocks desync naturally -> memory/compute phases stagger.
// Fragment maps (m89-verified, same as passing R3-R6):
//   A: lane l -> A[m=l&15][k=(l>>4)*8+i]
//   B: lane l -> B[k=(l>>4)*8+i][n=l&15]
//   C: lane l, reg r -> [m=(l>>4)*4+r][n=l&15]

#define TILE_TOK 16
#define NTILES 4

typedef __attribute__((ext_vector_type(8))) short short8;
typedef __attribute__((ext_vector_type(4))) float f32x4;

__device__ inline unsigned short f2bf(float f) {
    unsigned u = __float_as_uint(f);
    u += 0x7FFF + ((u >> 16) & 1);          // RNE
    return (unsigned short)(u >> 16);
}

__device__ inline short8 pack_bf16x8(float4 a, float4 b) {
    short8 r;
    r[0] = (short)f2bf(a.x); r[1] = (short)f2bf(a.y);
    r[2] = (short)f2bf(a.z); r[3] = (short)f2bf(a.w);
    r[4] = (short)f2bf(b.x); r[5] = (short)f2bf(b.y);
    r[6] = (short)f2bf(b.z); r[7] = (short)f2bf(b.w);
    return r;
}

__global__ __launch_bounds__(256, 4)
void mhaq_fused7(const float* __restrict__ x,
                 const float* __restrict__ theta,
                 const float* __restrict__ W,
                 const float* __restrict__ bias,
                 float* __restrict__ out,
                 int n_tokens)
{
    __shared__ __align__(16) float          zs[TILE_TOK * 68]; // f32, pad 4
    __shared__ __align__(16) unsigned short os[TILE_TOK * 72]; // bf16, pad 8

    const int tid  = threadIdx.x;
    const int tl   = tid >> 4;          // token within tile, 0..15
    const int s    = tid & 15;
    const int h    = s >> 1;            // head this thread attends
    const int half = s & 1;             // t-range / d-range half
    const int blockbase = blockIdx.x * (TILE_TOK * NTILES);
    const bool zrole = (s < 8);

    const int lane = tid & 63;
    const int wave = tid >> 6;          // 0..3 -> j-quarter
    const int lr   = lane & 15;
    const int lg   = lane >> 4;         // 0..3
    const int j    = wave * 16 + lr;

    // ---- tile-0 x load FIRST (phase-1 critical path) ----
    const float4* __restrict__ xp4 = reinterpret_cast<const float4*>(x);
    float4 xa = make_float4(0.f, 0.f, 0.f, 0.f);
    float4 xb = make_float4(0.f, 0.f, 0.f, 0.f);
    if (zrole && blockbase + tl < n_tokens) {
        const float4* p = xp4 + (size_t)(blockbase + tl) * 16 + s * 2;
        xa = p[0]; xb = p[1];
    }

    // ---- W + bias, ONCE per block (consumed/packed in tile-0 phase 3) ----
    float4 wf[2][2];                    // [kt][half8]
    float  bj = bias[j];
    {
        const float4* __restrict__ Wv = reinterpret_cast<const float4*>(W);
        #pragma unroll
        for (int kt = 0; kt < 2; ++kt) {
            int fidx = (j * 64 + kt * 32 + lg * 8) >> 2;
            wf[kt][0] = Wv[fidx];
            wf[kt][1] = Wv[fidx + 1];
        }
    }

    short8 bfrag0, bfrag1;              // packed W, set at t==0

    #pragma unroll
    for (int t = 0; t < NTILES; ++t) {
        const int tilebase = blockbase + t * TILE_TOK;

        // ---- issue next tile's x loads (stay in flight through compute) ----
        float4 xa_n = make_float4(0.f, 0.f, 0.f, 0.f);
        float4 xb_n = make_float4(0.f, 0.f, 0.f, 0.f);
        if (t + 1 < NTILES && zrole && tilebase + TILE_TOK + tl < n_tokens) {
            const float4* p = xp4 + (size_t)(tilebase + TILE_TOK + tl) * 16 + s * 2;
            xa_n = p[0]; xb_n = p[1];
        }

        // ---- phase 1: threads s<8 compute z for head s ----
        if (zrole) {
            float c0 = __cosf(xa.x + theta[0]);
            float c1 = __cosf(xa.y + theta[1]);
            float c2 = __cosf(xa.z + theta[2]);
            float c3 = __cosf(xa.w + theta[3]);
            float c4 = __cosf(xb.x + theta[4]);
            float c5 = __cosf(xb.y + theta[5]);
            float c6 = __cosf(xb.z + theta[6]);
            float c7 = __cosf(xb.w + theta[7]);
            float p1 = c0 * c1;
            float p2 = p1 * c2;
            float p3 = p2 * c3;
            float p4 = p3 * c4;
            float p5 = p4 * c5;
            float p6 = p5 * c6;
            float p7 = p6 * c7;
            float s6 = c6 * c7;
            float s5 = c5 * s6;
            float s4 = c4 * s5;
            float s3 = c3 * s4;
            float s2 = c2 * s3;
            float s1 = c1 * s2;         // c1*...*c7
            float4* z4 = reinterpret_cast<float4*>(zs + tl * 68 + s * 8);
            z4[0] = make_float4(s1, p1, p2, p3);
            z4[1] = make_float4(p4, p5, p6, p7);
        }
        __syncthreads();

        // ---- phase 2: head h, halves of t and d; o -> bf16 LDS ----
        {
            const float* zrow = zs + tl * 68;
            float zh[8];
            *reinterpret_cast<float4*>(&zh[0]) =
                *reinterpret_cast<const float4*>(&zrow[h * 8]);
            *reinterpret_cast<float4*>(&zh[4]) =
                *reinterpret_cast<const float4*>(&zrow[h * 8 + 4]);

            float zt[32];               // score rows t = half*4 .. +3
            #pragma unroll
            for (int i = 0; i < 8; ++i)
                *reinterpret_cast<float4*>(&zt[i * 4]) =
                    *reinterpret_cast<const float4*>(&zrow[half * 32 + i * 4]);

            const float scale = 0.35355339059327373f;  // 1/sqrt(8)
            float e[4];
            float psum = 0.f;
            #pragma unroll
            for (int tt = 0; tt < 4; ++tt) {
                float sd = 0.f;
                #pragma unroll
                for (int d = 0; d < 8; ++d)
                    sd = fmaf(zh[d], zt[tt * 8 + d], sd);
                e[tt] = __expf(sd * scale);
                psum += e[tt];
            }
            float tot = psum + __shfl_xor(psum, 1, 64);
            float inv = 1.0f / tot;

            float ep[4];
            #pragma unroll
            for (int tt = 0; tt < 4; ++tt)
                ep[tt] = __shfl_xor(e[tt], 1, 64);

            float ef[8];                // full e in t-order (static idx)
            #pragma unroll
            for (int tt = 0; tt < 4; ++tt) {
                ef[tt]     = half ? ep[tt] : e[tt];
                ef[4 + tt] = half ? e[tt]  : ep[tt];
            }

            float zc[32];               // z[t][half*4 + dd], t=0..7
            #pragma unroll
            for (int tt = 0; tt < 8; ++tt)
                *reinterpret_cast<float4*>(&zc[tt * 4]) =
                    *reinterpret_cast<const float4*>(&zrow[tt * 8 + half * 4]);

            unsigned short oh[4];
            #pragma unroll
            for (int dd = 0; dd < 4; ++dd) {
                float acc = 0.f;
                #pragma unroll
                for (int tt = 0; tt < 8; ++tt)
                    acc = fmaf(ef[tt], zc[tt * 4 + dd], acc);
                oh[dd] = f2bf(acc * inv);
            }
            *reinterpret_cast<ushort4*>(&os[tl * 72 + h * 8 + half * 4]) =
                make_ushort4(oh[0], oh[1], oh[2], oh[3]);
        }
        __syncthreads();

        // ---- phase 3: y = o @ W^T + b via MFMA ----
        {
            if (t == 0) {               // compile-time: pack W once
                bfrag0 = pack_bf16x8(wf[0][0], wf[0][1]);
                bfrag1 = pack_bf16x8(wf[1][0], wf[1][1]);
            }
            short8 afrag0 = *reinterpret_cast<const short8*>(&os[lr * 72 + lg * 8]);
            short8 afrag1 = *reinterpret_cast<const short8*>(&os[lr * 72 + 32 + lg * 8]);

            f32x4 acc = {bj, bj, bj, bj};
            acc = __builtin_amdgcn_mfma_f32_16x16x32_bf16(afrag0, bfrag0, acc, 0, 0, 0);
            acc = __builtin_amdgcn_mfma_f32_16x16x32_bf16(afrag1, bfrag1, acc, 0, 0, 0);

            #pragma unroll
            for (int r = 0; r < 4; ++r) {
                int trow = tilebase + lg * 4 + r;
                if (trow < n_tokens)
                    out[(size_t)trow * 64 + j] = acc[r];
            }
        }

        xa = xa_n; xb = xb_n;
    }
}

extern "C" void kernel_launch(void* const* d_in, const int* in_sizes, int n_in,
                              void* d_out, int out_size, void* d_ws, size_t ws_size,
                              hipStream_t stream)
{
    const float* x     = (const float*)d_in[0];
    const float* theta = (const float*)d_in[1];
    const float* W     = (const float*)d_in[2];
    const float* b     = (const float*)d_in[3];
    float* out         = (float*)d_out;

    const int n_tokens  = in_sizes[0] / 64;                     // 16384
    const int tok_blk   = TILE_TOK * NTILES;                    // 64
    const int blocks    = (n_tokens + tok_blk - 1) / tok_blk;   // 256
    mhaq_fused7<<<blocks, 256, 0, stream>>>(x, theta, W, b, out, n_tokens);
}